// Round 14
// baseline (96.625 us; speedup 1.0000x reference)
//
#include <hip/hip_runtime.h>
#include <math.h>

// Problem constants (B,C,H,W = 16,64,256,256; RATIO=2, GROUPS=4)
#define BATCH 16
#define CIN   64
#define HIN   256
#define WIN   256
#define HOUT  128
#define WOUT  128
#define NPIX  (HIN * WIN)          // 65536
#define NPIXO (HOUT * WOUT)        // 16384
#define OUT0_SIZE ((size_t)BATCH * CIN * HOUT * WOUT)   // 16777216

// ---------------------------------------------------------------------------
// v9 = r13 (92.6us: fused body + XCD pair-locality swizzle) + L2-remnant
// preservation in phase 2:
//   (a) gather loads are NONTEMPORAL: gathered lines are use-once (each is
//       consumed by exactly one partner block), so their miss-fills must not
//       evict the phase-1 remnants other blocks still need;
//   (b) phase-2 channel walk REVERSED (g=3..0, c=15..0): phase 1 streamed
//       channels ascending, so the freshest L2 lines are the highest
//       channels — gather those before miss/write pressure evicts them.
// ---------------------------------------------------------------------------
__global__ __launch_bounds__(256) void k_fused(
    const float* __restrict__ x,
    const float* __restrict__ w_off, const float* __restrict__ b_off,
    const float* __restrict__ w_sc,  const float* __restrict__ b_sc,
    float* __restrict__ out, float* __restrict__ offg)
{
    __shared__ float  sw[256];            // w_off ch0/ch1, w_sc ch0/ch1
    __shared__ float2 soff[4][16][17];    // [grp][row][col], padded
    __shared__ float  sval[16][272];      // [c][hl*17+wl], one group at a time

    int t = threadIdx.x;
    sw[t] = (t < 128) ? w_off[t] : w_sc[t - 128];

    // ---- XCD pair-locality decode (r13) ----
    int g_   = blockIdx.x;        // [0,1024)
    int xcd  = g_ & 7;
    int pos  = g_ >> 3;           // per-XCD slot [0,128)
    int b, th, tw;
    if (pos < 112) {
        int s = pos >> 1, side = pos & 1;
        int v = xcd * 56 + s;     // off-diagonal pair unit [0,448)
        b = v / 28;
        int pidx = v - b * 28;    // strict upper-triangle index [0,28)
        int i = 0;
        while (pidx >= 7 - i) { pidx -= 7 - i; ++i; }
        int j = i + 1 + pidx;
        th = side ? j : i;
        tw = side ? i : j;
    } else {
        int w_ = xcd * 16 + (pos - 112);   // diagonal unit [0,128)
        b = w_ >> 3;
        th = tw = w_ & 7;
    }
    int hh0 = th * 16, ww0 = tw * 16;

    // ---------------- phase 1: conv1x1 offsets ----------------
    int row = t >> 4, col = t & 15;       // ww-fast mapping
    int hh = hh0 + row, ww = ww0 + col;

    const float* xb = x + (size_t)b * CIN * NPIX + (2 * hh) * WIN + 2 * ww;

    float aA0[2][2] = {{0,0},{0,0}}, aA1[2][2] = {{0,0},{0,0}};
    float aS0[2][2] = {{0,0},{0,0}}, aS1[2][2] = {{0,0},{0,0}};

    __syncthreads();   // sw ready

    #pragma unroll 8
    for (int c = 0; c < CIN; ++c) {
        const float* xc = xb + (size_t)c * NPIX;
        float2 r0 = *reinterpret_cast<const float2*>(xc);        // row 2hh
        float2 r1 = *reinterpret_cast<const float2*>(xc + WIN);  // row 2hh+1
        float wo0 = sw[c], wo1 = sw[64 + c], ws0 = sw[128 + c], ws1 = sw[192 + c];
        aA0[0][0] += r0.x * wo0;  aA0[0][1] += r0.y * wo0;
        aA0[1][0] += r1.x * wo0;  aA0[1][1] += r1.y * wo0;
        aA1[0][0] += r0.x * wo1;  aA1[0][1] += r0.y * wo1;
        aA1[1][0] += r1.x * wo1;  aA1[1][1] += r1.y * wo1;
        aS0[0][0] += r0.x * ws0;  aS0[0][1] += r0.y * ws0;
        aS0[1][0] += r1.x * ws0;  aS0[1][1] += r1.y * ws0;
        aS1[0][0] += r0.x * ws1;  aS1[0][1] += r0.y * ws1;
        aS1[1][0] += r1.x * ws1;  aS1[1][1] += r1.y * ws1;
    }

    float bo0 = b_off[0], bo1 = b_off[1];
    float bs0 = b_sc[0],  bs1 = b_sc[1];

    // offg[grp][two]: grp = 2*o + i (conv row parity), two = j (col parity)
    float og[4][2];
    #pragma unroll
    for (int i = 0; i < 2; ++i) {
        #pragma unroll
        for (int j = 0; j < 2; ++j) {
            float g0 = 1.0f / (1.0f + __expf(-(aS0[i][j] + bs0)));
            float g1 = 1.0f / (1.0f + __expf(-(aS1[i][j] + bs1)));
            og[i][j]     = g0 * 0.5f * (aA0[i][j] + bo0);
            og[2 + i][j] = g1 * 0.5f * (aA1[i][j] + bo1);
        }
    }

    #pragma unroll
    for (int g = 0; g < 4; ++g) {
        float2 vv = make_float2(og[g][0], og[g][1]);
        soff[g][row][col] = vv;
        size_t oi = ((size_t)((b * 4 + g) * HOUT + hh)) * WOUT + ww;
        __builtin_nontemporal_store(__builtin_bit_cast(double, vv),
                                    reinterpret_cast<double*>(offg + 2 * oi));
    }
    __syncthreads();

    // ---------------- phase 2: bilinear grid sample, group-sequential ------
    int hl = t & 15, wl = t >> 4;          // hh-fast: gather coalescing
    int shh = hh0 + hl, sww = ww0 + wl;
    const float* xg = x + (size_t)b * CIN * NPIX;

    int sh = t >> 4, sc = t & 15;          // store mapping (ww-fast)
    float* ob = out + (((size_t)b * CIN) * HOUT + (hh0 + sh)) * WOUT + (ww0 + sc);

    // reversed channel walk: freshest L2 lines (highest channels) first
    for (int g = 3; g >= 0; --g) {
        float2 off = soff[g][hl][wl];
        // transposed coords: ix (column) from hh, iy (row) from ww
        float ix = 2.0f * ((float)shh + 0.5f + off.x) - 0.5f;
        float iy = 2.0f * ((float)sww + 0.5f + off.y) - 0.5f;
        ix = fminf(fmaxf(ix, 0.0f), (float)(WIN - 1));
        iy = fminf(fmaxf(iy, 0.0f), (float)(HIN - 1));

        float x0f = floorf(ix), y0f = floorf(iy);
        float wx = ix - x0f, wy = iy - y0f;
        int x0 = (int)x0f, y0 = (int)y0f;
        int x1 = min(x0 + 1, WIN - 1);
        int y1 = min(y0 + 1, HIN - 1);

        float w00 = (1.0f - wx) * (1.0f - wy);
        float w01 = wx * (1.0f - wy);
        float w10 = (1.0f - wx) * wy;
        float w11 = wx * wy;

        int i00 = y0 * WIN + x0, i01 = y0 * WIN + x1;
        int i10 = y1 * WIN + x0, i11 = y1 * WIN + x1;

        const float* xgc = xg + (size_t)g * NPIX;   // channel c*4+g

        float v[16];
        // fast path: x0 even with real right neighbor -> aligned float2 loads
        bool fastp = ((x0 & 1) == 0) && (x1 == x0 + 1);
        if (fastp) {
            #pragma unroll
            for (int c = 15; c >= 0; --c) {
                const float* xc = xgc + (size_t)c * 4 * NPIX;
                double da = __builtin_nontemporal_load(
                    reinterpret_cast<const double*>(xc + i00));
                double dd = __builtin_nontemporal_load(
                    reinterpret_cast<const double*>(xc + i10));
                float2 a = __builtin_bit_cast(float2, da);
                float2 d = __builtin_bit_cast(float2, dd);
                v[c] = a.x * w00 + a.y * w01 + d.x * w10 + d.y * w11;
            }
        } else {
            #pragma unroll
            for (int c = 15; c >= 0; --c) {
                const float* xc = xgc + (size_t)c * 4 * NPIX;
                float f00 = __builtin_nontemporal_load(xc + i00);
                float f01 = __builtin_nontemporal_load(xc + i01);
                float f10 = __builtin_nontemporal_load(xc + i10);
                float f11 = __builtin_nontemporal_load(xc + i11);
                v[c] = f00 * w00 + f01 * w01 + f10 * w10 + f11 * w11;
            }
        }

        __syncthreads();   // previous group's sval reads complete
        #pragma unroll
        for (int c = 0; c < 16; ++c)
            sval[c][hl * 17 + wl] = v[c];
        __syncthreads();   // sval ready

        // coalesced nontemporal stores
        #pragma unroll
        for (int c = 0; c < 16; ++c)
            __builtin_nontemporal_store(sval[c][sh * 17 + sc],
                                        &ob[(size_t)(c * 4 + g) * NPIXO]);
    }
}

extern "C" void kernel_launch(void* const* d_in, const int* in_sizes, int n_in,
                              void* d_out, int out_size, void* d_ws, size_t ws_size,
                              hipStream_t stream) {
    const float* x     = (const float*)d_in[0];
    const float* w_off = (const float*)d_in[1];
    const float* b_off = (const float*)d_in[2];
    const float* w_sc  = (const float*)d_in[3];
    const float* b_sc  = (const float*)d_in[4];

    float* out  = (float*)d_out;
    float* offg = out + OUT0_SIZE;   // second return value, concatenated

    // 1024 blocks (16 batches x 64 tiles), XCD-pair-swizzled decode in-kernel
    k_fused<<<1024, 256, 0, stream>>>(x, w_off, b_off, w_sc, b_sc, out, offg);
}

// Round 15
// 92.653 us; speedup vs baseline: 1.0429x; 1.0429x over previous
//
#include <hip/hip_runtime.h>
#include <math.h>

// Problem constants (B,C,H,W = 16,64,256,256; RATIO=2, GROUPS=4)
#define BATCH 16
#define CIN   64
#define HIN   256
#define WIN   256
#define HOUT  128
#define WOUT  128
#define NPIX  (HIN * WIN)          // 65536
#define NPIXO (HOUT * WOUT)        // 16384
#define OUT0_SIZE ((size_t)BATCH * CIN * HOUT * WOUT)   // 16777216

// ---------------------------------------------------------------------------
// FINAL (r13 revert): fused conv-offsets + grid-sample, XCD pair-locality.
//
// Roofline accounting (measured over r6-r14):
//   fabric bytes = 268MB conv-read (HBM, exactly once: FETCH=262MB)
//                + ~228MB gather (L3/L2-served; L2-remnant hits via pair
//                  swizzle recovered ~40MB — the r13 -5us win)
//                + 84MB NT writes  ==> ~583MB @ ~6.3TB/s = ~92us measured.
//   Tested-null: occupancy 2x (r7), VMEM count /2 (r9), producer/consumer
//   overlap (r10), LDS retention f32/bf16 (r11/r12 — 64B-granule HBM reads
//   run at 2.2-2.7TB/s, killing the 352MB floor), NT gathers + reversed
//   walk (r14, -4%). The 352MB arithmetic floor is unreachable: <4MB reuse
//   distance and >=128B HBM granularity cannot coexist on this op.
//
// Identity: gather region of tile (th,tw) == conv square of partner (tw,th)
// (the op transposes coordinates: ix from hh, iy from ww). The block decode
// co-locates each pair {(i,j),(j,i)} on one XCD at adjacent slots so the
// partner's phase-2 gathers hit that XCD's own L2 remnants.
// ---------------------------------------------------------------------------
__global__ __launch_bounds__(256) void k_fused(
    const float* __restrict__ x,
    const float* __restrict__ w_off, const float* __restrict__ b_off,
    const float* __restrict__ w_sc,  const float* __restrict__ b_sc,
    float* __restrict__ out, float* __restrict__ offg)
{
    __shared__ float  sw[256];            // w_off ch0/ch1, w_sc ch0/ch1
    __shared__ float2 soff[4][16][17];    // [grp][row][col], padded
    __shared__ float  sval[16][272];      // [c][hl*17+wl], one group at a time

    int t = threadIdx.x;
    sw[t] = (t < 128) ? w_off[t] : w_sc[t - 128];

    // ---- XCD pair-locality decode ----
    int g_   = blockIdx.x;        // [0,1024)
    int xcd  = g_ & 7;
    int pos  = g_ >> 3;           // per-XCD slot [0,128)
    int b, th, tw;
    if (pos < 112) {
        int s = pos >> 1, side = pos & 1;
        int v = xcd * 56 + s;     // off-diagonal pair unit [0,448)
        b = v / 28;
        int pidx = v - b * 28;    // strict upper-triangle index [0,28)
        int i = 0;
        while (pidx >= 7 - i) { pidx -= 7 - i; ++i; }
        int j = i + 1 + pidx;
        th = side ? j : i;
        tw = side ? i : j;
    } else {
        int w_ = xcd * 16 + (pos - 112);   // diagonal unit [0,128)
        b = w_ >> 3;
        th = tw = w_ & 7;
    }
    int hh0 = th * 16, ww0 = tw * 16;

    // ---------------- phase 1: conv1x1 offsets ----------------
    int row = t >> 4, col = t & 15;       // ww-fast mapping
    int hh = hh0 + row, ww = ww0 + col;

    const float* xb = x + (size_t)b * CIN * NPIX + (2 * hh) * WIN + 2 * ww;

    float aA0[2][2] = {{0,0},{0,0}}, aA1[2][2] = {{0,0},{0,0}};
    float aS0[2][2] = {{0,0},{0,0}}, aS1[2][2] = {{0,0},{0,0}};

    __syncthreads();   // sw ready

    #pragma unroll 8
    for (int c = 0; c < CIN; ++c) {
        const float* xc = xb + (size_t)c * NPIX;
        float2 r0 = *reinterpret_cast<const float2*>(xc);        // row 2hh
        float2 r1 = *reinterpret_cast<const float2*>(xc + WIN);  // row 2hh+1
        float wo0 = sw[c], wo1 = sw[64 + c], ws0 = sw[128 + c], ws1 = sw[192 + c];
        aA0[0][0] += r0.x * wo0;  aA0[0][1] += r0.y * wo0;
        aA0[1][0] += r1.x * wo0;  aA0[1][1] += r1.y * wo0;
        aA1[0][0] += r0.x * wo1;  aA1[0][1] += r0.y * wo1;
        aA1[1][0] += r1.x * wo1;  aA1[1][1] += r1.y * wo1;
        aS0[0][0] += r0.x * ws0;  aS0[0][1] += r0.y * ws0;
        aS0[1][0] += r1.x * ws0;  aS0[1][1] += r1.y * ws0;
        aS1[0][0] += r0.x * ws1;  aS1[0][1] += r0.y * ws1;
        aS1[1][0] += r1.x * ws1;  aS1[1][1] += r1.y * ws1;
    }

    float bo0 = b_off[0], bo1 = b_off[1];
    float bs0 = b_sc[0],  bs1 = b_sc[1];

    // offg[grp][two]: grp = 2*o + i (conv row parity), two = j (col parity)
    float og[4][2];
    #pragma unroll
    for (int i = 0; i < 2; ++i) {
        #pragma unroll
        for (int j = 0; j < 2; ++j) {
            float g0 = 1.0f / (1.0f + __expf(-(aS0[i][j] + bs0)));
            float g1 = 1.0f / (1.0f + __expf(-(aS1[i][j] + bs1)));
            og[i][j]     = g0 * 0.5f * (aA0[i][j] + bo0);
            og[2 + i][j] = g1 * 0.5f * (aA1[i][j] + bo1);
        }
    }

    #pragma unroll
    for (int g = 0; g < 4; ++g) {
        float2 vv = make_float2(og[g][0], og[g][1]);
        soff[g][row][col] = vv;
        size_t oi = ((size_t)((b * 4 + g) * HOUT + hh)) * WOUT + ww;
        // nontemporal 8B store: offg is write-only output, keep it out of cache
        __builtin_nontemporal_store(__builtin_bit_cast(double, vv),
                                    reinterpret_cast<double*>(offg + 2 * oi));
    }
    __syncthreads();

    // ---------------- phase 2: bilinear grid sample, group-sequential ------
    int hl = t & 15, wl = t >> 4;          // hh-fast: gather coalescing
    int shh = hh0 + hl, sww = ww0 + wl;
    const float* xg = x + (size_t)b * CIN * NPIX;

    int sh = t >> 4, sc = t & 15;          // store mapping (ww-fast)
    float* ob = out + (((size_t)b * CIN) * HOUT + (hh0 + sh)) * WOUT + (ww0 + sc);

    for (int g = 0; g < 4; ++g) {
        float2 off = soff[g][hl][wl];
        // transposed coords: ix (column) from hh, iy (row) from ww
        float ix = 2.0f * ((float)shh + 0.5f + off.x) - 0.5f;
        float iy = 2.0f * ((float)sww + 0.5f + off.y) - 0.5f;
        ix = fminf(fmaxf(ix, 0.0f), (float)(WIN - 1));
        iy = fminf(fmaxf(iy, 0.0f), (float)(HIN - 1));

        float x0f = floorf(ix), y0f = floorf(iy);
        float wx = ix - x0f, wy = iy - y0f;
        int x0 = (int)x0f, y0 = (int)y0f;
        int x1 = min(x0 + 1, WIN - 1);
        int y1 = min(y0 + 1, HIN - 1);

        float w00 = (1.0f - wx) * (1.0f - wy);
        float w01 = wx * (1.0f - wy);
        float w10 = (1.0f - wx) * wy;
        float w11 = wx * wy;

        int i00 = y0 * WIN + x0, i01 = y0 * WIN + x1;
        int i10 = y1 * WIN + x0, i11 = y1 * WIN + x1;

        const float* xgc = xg + (size_t)g * NPIX;   // channel c*4+g

        float v[16];
        // fast path: x0 even with real right neighbor -> aligned float2 loads
        bool fastp = ((x0 & 1) == 0) && (x1 == x0 + 1);
        if (fastp) {
            #pragma unroll
            for (int c = 0; c < 16; ++c) {
                const float* xc = xgc + (size_t)c * 4 * NPIX;
                float2 a = *reinterpret_cast<const float2*>(xc + i00);
                float2 d = *reinterpret_cast<const float2*>(xc + i10);
                v[c] = a.x * w00 + a.y * w01 + d.x * w10 + d.y * w11;
            }
        } else {
            #pragma unroll
            for (int c = 0; c < 16; ++c) {
                const float* xc = xgc + (size_t)c * 4 * NPIX;
                v[c] = xc[i00] * w00 + xc[i01] * w01
                     + xc[i10] * w10 + xc[i11] * w11;
            }
        }

        __syncthreads();   // previous group's sval reads complete
        #pragma unroll
        for (int c = 0; c < 16; ++c)
            sval[c][hl * 17 + wl] = v[c];
        __syncthreads();   // sval ready

        // coalesced nontemporal stores (don't evict x from cache)
        #pragma unroll
        for (int c = 0; c < 16; ++c)
            __builtin_nontemporal_store(sval[c][sh * 17 + sc],
                                        &ob[(size_t)(c * 4 + g) * NPIXO]);
    }
}

extern "C" void kernel_launch(void* const* d_in, const int* in_sizes, int n_in,
                              void* d_out, int out_size, void* d_ws, size_t ws_size,
                              hipStream_t stream) {
    const float* x     = (const float*)d_in[0];
    const float* w_off = (const float*)d_in[1];
    const float* b_off = (const float*)d_in[2];
    const float* w_sc  = (const float*)d_in[3];
    const float* b_sc  = (const float*)d_in[4];

    float* out  = (float*)d_out;
    float* offg = out + OUT0_SIZE;   // second return value, concatenated

    // 1024 blocks (16 batches x 64 tiles), XCD-pair-swizzled decode in-kernel
    k_fused<<<1024, 256, 0, stream>>>(x, w_off, b_off, w_sc, b_sc, out, offg);
}